// Round 3
// baseline (553.404 us; speedup 1.0000x reference)
//
#include <hip/hip_runtime.h>
#include <hip/hip_bf16.h>
#include <math.h>

#define EMBED 1024
#define HIDDEN 128
#define NPROTO 512

typedef short bf16x8 __attribute__((ext_vector_type(8)));
typedef int   i32x4  __attribute__((ext_vector_type(4)));
typedef float f32x4  __attribute__((ext_vector_type(4)));

__device__ __forceinline__ unsigned short f2bf(float x) {
    unsigned u = __builtin_bit_cast(unsigned, x);
    unsigned r = u + 0x7FFFu + ((u >> 16) & 1u);   // round-to-nearest-even
    return (unsigned short)(r >> 16);
}

// round-half-up bf16 pair pack: 3 ops per 2 elements (vs ~10 for RNE)
__device__ __forceinline__ unsigned pack_bf2(float x, float y) {
    unsigned ux = __builtin_bit_cast(unsigned, x) + 0x8000u;
    unsigned uy = __builtin_bit_cast(unsigned, y) + 0x8000u;
    return (uy & 0xFFFF0000u) | (ux >> 16);
}
__device__ __forceinline__ bf16x8 pack_bf8(float4 a, float4 b) {
    i32x4 r;
    r.x = (int)pack_bf2(a.x, a.y); r.y = (int)pack_bf2(a.z, a.w);
    r.z = (int)pack_bf2(b.x, b.y); r.w = (int)pack_bf2(b.z, b.w);
    return __builtin_bit_cast(bf16x8, r);
}

// Prep: blocks 0..255  -> proto_h rows 2b, 2b+1 (fp32 GEMV, K=1024)
//       blocks 256..319 -> w1t = bf16(W1[0:1024])^T, [n][k] layout
__global__ __launch_bounds__(256) void prep_kernel(
    const float* __restrict__ prototypes,   // [512][1024]
    const float* __restrict__ W1,           // [2048][128]
    float* __restrict__ proto_h,            // ws [512][128]
    unsigned short* __restrict__ w1t)       // ws [128][1024] bf16
{
    int b = blockIdx.x;
    int t = threadIdx.x;
    if (b < 256) {
        int ph = t >> 7, h = t & 127;
        int p = b * 2 + ph;
        const float* pr = prototypes + (size_t)p * EMBED;
        const float* w  = W1 + (size_t)EMBED * HIDDEN + h;   // bottom half, col h
        float acc = 0.f;
        for (int k = 0; k < EMBED; k += 8) {
            #pragma unroll
            for (int j = 0; j < 8; ++j)
                acc += pr[k + j] * w[(size_t)(k + j) * HIDDEN];
        }
        proto_h[(size_t)p * HIDDEN + h] = acc;
    } else {
        int s = (b - 256) * 256 + t;        // 0..16383
        int n = s & 127;
        int k0 = (s >> 7) * 8;
        bf16x8 v;
        #pragma unroll
        for (int j = 0; j < 8; ++j)
            v[j] = (short)f2bf(W1[(size_t)(k0 + j) * HIDDEN + n]);
        *(bf16x8*)(w1t + (size_t)n * EMBED + k0) = v;
    }
}

// Fused, barrier-free K-loop: argmin -> q@W1_top (MFMA, A and B direct from
// global) + proto_h[idx] + b1 -> relu -> dot W2 -> sigmoid.
// 64 queries/block; wave w owns rows w*16..w*16+15 across ALL 128 hidden units.
__global__ __launch_bounds__(256, 4) void main_kernel(
    const float* __restrict__ qf,           // [65536][1024]
    const float* __restrict__ dist,         // [65536][512]
    const float* __restrict__ b1,           // [128]
    const float* __restrict__ W2,           // [128]
    const float* __restrict__ b2,           // [1]
    const float* __restrict__ proto_h,      // [512][128]
    const unsigned short* __restrict__ w1t, // [128][1024] bf16
    float* __restrict__ out)                // [65536]
{
    __shared__ int s_idx[64];

    int t = threadIdx.x;
    int wave = t >> 6, lane = t & 63;
    int quad = lane >> 4, tid16 = lane & 15;
    int q0 = blockIdx.x * 64;

    // ---- Phase 1: argmin over 512 distances; wave w -> queries w*16..+15,
    //      4-way unrolled so the shuffle-reduce chains interleave.
    for (int i = 0; i < 16; i += 4) {
        float4 v0[4], v1[4];
        #pragma unroll
        for (int j = 0; j < 4; ++j) {
            const float* dr = dist + (size_t)(q0 + wave * 16 + i + j) * NPROTO;
            v0[j] = ((const float4*)dr)[lane];
            v1[j] = ((const float4*)dr)[lane + 64];
        }
        #pragma unroll
        for (int j = 0; j < 4; ++j) {
            float bv = v0[j].x; int bi = lane * 4;
            if (v0[j].y < bv) { bv = v0[j].y; bi = lane * 4 + 1; }
            if (v0[j].z < bv) { bv = v0[j].z; bi = lane * 4 + 2; }
            if (v0[j].w < bv) { bv = v0[j].w; bi = lane * 4 + 3; }
            int c = 256 + lane * 4;
            if (v1[j].x < bv) { bv = v1[j].x; bi = c; }
            if (v1[j].y < bv) { bv = v1[j].y; bi = c + 1; }
            if (v1[j].z < bv) { bv = v1[j].z; bi = c + 2; }
            if (v1[j].w < bv) { bv = v1[j].w; bi = c + 3; }
            #pragma unroll
            for (int s = 1; s < 64; s <<= 1) {
                float ov = __shfl_xor(bv, s);
                int   oi = __shfl_xor(bi, s);
                if (ov < bv || (ov == bv && oi < bi)) { bv = ov; bi = oi; }
            }
            if (lane == 0) s_idx[wave * 16 + i + j] = bi;
        }
    }
    __syncthreads();   // only barrier in the kernel (s_idx for epilogue)

    // ---- Phase 2: MFMA over K=1024, BK=64, no LDS, no barriers.
    // A frag (16x16x32): lane -> A[m=tid16][k=quad*8+j]; row = q0+wave*16+tid16.
    // B frag: lane -> B[n=tid16][k=quad*8+j] from w1t rows n (L2-resident).
    f32x4 acc[8];
    #pragma unroll
    for (int ni = 0; ni < 8; ++ni) acc[ni] = (f32x4){0.f, 0.f, 0.f, 0.f};

    const float* abase = qf + (size_t)(q0 + wave * 16 + tid16) * EMBED + quad * 8;
    const unsigned short* bbase = w1t + (size_t)tid16 * EMBED + quad * 8;

    for (int kt = 0; kt < EMBED; kt += 64) {
        // A: 8 consecutive floats per lane for each of the two K-halves (HBM)
        float4 a0 = *(const float4*)(abase + kt);
        float4 a1 = *(const float4*)(abase + kt + 4);
        float4 a2 = *(const float4*)(abase + kt + 32);
        float4 a3 = *(const float4*)(abase + kt + 36);

        bf16x8 bfr[8];
        #pragma unroll
        for (int ni = 0; ni < 8; ++ni)
            bfr[ni] = *(const bf16x8*)(bbase + (size_t)(ni * 16) * EMBED + kt);
        bf16x8 af0 = pack_bf8(a0, a1);
        #pragma unroll
        for (int ni = 0; ni < 8; ++ni)
            acc[ni] = __builtin_amdgcn_mfma_f32_16x16x32_bf16(af0, bfr[ni], acc[ni], 0, 0, 0);

        #pragma unroll
        for (int ni = 0; ni < 8; ++ni)
            bfr[ni] = *(const bf16x8*)(bbase + (size_t)(ni * 16) * EMBED + kt + 32);
        bf16x8 af1 = pack_bf8(a2, a3);
        #pragma unroll
        for (int ni = 0; ni < 8; ++ni)
            acc[ni] = __builtin_amdgcn_mfma_f32_16x16x32_bf16(af1, bfr[ni], acc[ni], 0, 0, 0);
    }

    // ---- Epilogue: + b1 + proto_h[idx], relu, * W2, in-wave reduce, sigmoid.
    // C/D layout: col(n%16)=tid16, n = ni*16+tid16; row = wave*16 + quad*4 + reg.
    float b1v[8], w2v[8];
    #pragma unroll
    for (int ni = 0; ni < 8; ++ni) {
        int n = ni * 16 + tid16;
        b1v[ni] = b1[n];
        w2v[ni] = W2[n];
    }
    float bias2 = b2[0];
    #pragma unroll
    for (int r = 0; r < 4; ++r) {
        int row = wave * 16 + quad * 4 + r;
        const float* ph = proto_h + (size_t)s_idx[row] * HIDDEN;
        float sum = 0.f;
        #pragma unroll
        for (int ni = 0; ni < 8; ++ni) {
            float v = acc[ni][r] + b1v[ni] + ph[ni * 16 + tid16];
            sum += fmaxf(v, 0.f) * w2v[ni];
        }
        #pragma unroll
        for (int s = 1; s < 16; s <<= 1) sum += __shfl_xor(sum, s);
        if (tid16 == 0)
            out[q0 + row] = 1.f / (1.f + expf(-(sum + bias2)));
    }
}

extern "C" void kernel_launch(void* const* d_in, const int* in_sizes, int n_in,
                              void* d_out, int out_size, void* d_ws, size_t ws_size,
                              hipStream_t stream) {
    const float* qf    = (const float*)d_in[0];   // [65536,1024]
    const float* proto = (const float*)d_in[1];   // [512,1024]
    const float* dist  = (const float*)d_in[2];   // [65536,512]
    const float* W1    = (const float*)d_in[3];   // [2048,128]
    const float* b1    = (const float*)d_in[4];   // [128]
    const float* W2    = (const float*)d_in[5];   // [128,1]
    const float* b2    = (const float*)d_in[6];   // [1]
    float* out = (float*)d_out;

    float* proto_h = (float*)d_ws;                                        // 256 KB
    unsigned short* w1t = (unsigned short*)((char*)d_ws + 512 * 128 * 4); // 256 KB

    prep_kernel<<<320, 256, 0, stream>>>(proto, W1, proto_h, w1t);

    int nq = in_sizes[0] / EMBED;  // 65536
    main_kernel<<<nq / 64, 256, 0, stream>>>(qf, dist, b1, W2, b2, proto_h, w1t, out);
}